// Round 1
// baseline (331.417 us; speedup 1.0000x reference)
//
#include <hip/hip_runtime.h>

#define B_DIM 8
#define C_DIM 256
#define I_DIM 128
#define N_DIM 4096
#define R_DIM 64

typedef unsigned short u16;
typedef unsigned int u32;
typedef __attribute__((ext_vector_type(8))) __bf16 bf16x8;
typedef __attribute__((ext_vector_type(4))) float f32x4;
typedef __attribute__((ext_vector_type(16))) float f32x16;

union BF8 { u32 u[4]; bf16x8 v; };

__device__ __forceinline__ u16 f2bf(float f) {
    union { float f; u32 u; } v; v.f = f;
    u32 r = v.u + 0x7FFFu + ((v.u >> 16) & 1u);
    return (u16)(r >> 16);
}
__device__ __forceinline__ float bf2f(u16 h) {
    union { u32 u; float f; } v; v.u = (u32)h << 16; return v.f;
}
__device__ __forceinline__ u32 pk2(float a, float b) {
    return (u32)f2bf(a) | ((u32)f2bf(b) << 16);
}
// truncating bf16 pack: [b.hi16 | a.hi16] in ONE v_perm_b32
__device__ __forceinline__ u32 pk2t(float a, float b) {
    union { float f; u32 u; } ua, ub; ua.f = a; ub.f = b;
    return __builtin_amdgcn_perm(ub.u, ua.u, 0x07060302u);
}
__device__ __forceinline__ void async16(const u16* g, u16* l) {
    __builtin_amdgcn_global_load_lds((const __attribute__((address_space(1))) void*)g,
                                     (__attribute__((address_space(3))) void*)l, 16, 0, 0);
}
// v_permlane32_swap: a' = [a.lo32 | b.lo32], b' = [a.hi32 | b.hi32]
__device__ __forceinline__ void plswap(u32& a, u32& b) {
    __asm__("v_permlane32_swap_b32 %0, %1" : "+v"(a), "+v"(b));
}

// log2(e)/sqrt(128), folded into theta at projection time
#define TH_SCALE 0.1275204890136f

// ---- workspace layout (bytes) ----
static constexpr size_t OFF_BNSUM = 0;
static constexpr size_t OFF_BNSQ  = 1024;
static constexpr size_t OFF_POOL  = 2048;
static constexpr size_t OFF_CHW   = 10240;
static constexpr size_t OFF_W3    = 18432;                  // 3*128*256 bf16
static constexpr size_t OFF_OWB   = 215040;                 // 256*128 bf16
static constexpr size_t OFF_AO0   = 280576;                 // [B,N,I] bf16 partial 0
static constexpr size_t OFF_AO1   = OFF_AO0 + 8388608;      // partial 1
static constexpr size_t OFF_THETA = OFF_AO1 + 8388608;      // [B,N,I] bf16 (pre-scaled)
static constexpr size_t OFF_PHIT  = OFF_THETA + 8388608;
static constexpr size_t OFF_GT    = OFF_PHIT + 8388608;     // [B,I,N] bf16
static constexpr size_t OFF_L0    = OFF_GT + 8388608;       // [B,N] f32
static constexpr size_t OFF_L1    = OFF_L0 + 131072;
static constexpr size_t OFF_OUT2  = OFF_L1 + 131072;        // [B,C,N] bf16

// ---- 1: weight convert + zero accumulators ----
__global__ void prep_kernel(const float* __restrict__ tw, const float* __restrict__ pw,
                            const float* __restrict__ gw, const float* __restrict__ ow,
                            u16* __restrict__ w3, u16* __restrict__ owb,
                            float* __restrict__ bnzero, float* __restrict__ pooled) {
    int idx = blockIdx.x * 256 + threadIdx.x;
    if (idx < 512) bnzero[idx] = 0.f;
    if (idx < 2048) pooled[idx] = 0.f;
    if (idx < 3 * 32768) {
        const float* src = idx < 32768 ? tw : (idx < 65536 ? pw : gw);
        w3[idx] = f2bf(src[idx & 32767]);
    }
    if (idx < 32768) owb[idx] = f2bf(ow[idx]);
}

// ---- 4: fused QKV projection (direct from x, 32x32x16 MFMA) + SE pooling ----
__global__ __launch_bounds__(256) void qkv_kernel(const float* __restrict__ x,
                                                  const u16* __restrict__ w3,
                                                  u16* __restrict__ theta,
                                                  u16* __restrict__ phiT,
                                                  u16* __restrict__ gT,
                                                  float* __restrict__ pooled) {
    const int bid = blockIdx.x;
    const int b = bid & 7, nt = bid >> 3;
    const int n0 = nt * 64;
    const int t = threadIdx.x, lane = t & 63, w = t >> 6;
    const int cl = lane & 31, h = lane >> 5;

    __shared__ u16 As[64 * 256];   // [n][c] bf16, 16B-granule swizzled ^(n&7)
    __shared__ u16 Ep[128 * 72];   // epilogue buffer

    {   // stage x[b, :, n0:n0+64] -> As (transposed to [n][c]); fused SE pooling
        const float* xb = x + ((size_t)b * C_DIM) * N_DIM + n0;
        for (int it = 0; it < 16; ++it) {
            int id = it * 256 + t;
            int c = id >> 4, l16 = id & 15;
            float4 v = *(const float4*)(xb + (size_t)c * N_DIM + l16 * 4);
            int g = c >> 3, co = c & 7;
            float vv[4] = {v.x, v.y, v.z, v.w};
            #pragma unroll
            for (int k = 0; k < 4; ++k) {
                int n = l16 * 4 + k;
                As[n * 256 + ((g ^ (n & 7)) << 3) + co] = f2bf(vv[k]);
            }
            float s = (v.x + v.y) + (v.z + v.w);
            s += __shfl_xor(s, 1); s += __shfl_xor(s, 2);
            s += __shfl_xor(s, 4); s += __shfl_xor(s, 8);
            if ((t & 15) == 0) atomicAdd(&pooled[b * C_DIM + c], s);
        }
    }
    __syncthreads();

    const int mt = w & 1;    // n-tile
    const int ip = w >> 1;   // i-pair
    bf16x8 afr[16];
    #pragma unroll
    for (int ks = 0; ks < 16; ++ks) {
        int r = mt * 32 + cl;
        int g = 2 * ks + h;
        afr[ks] = *(const bf16x8*)&As[r * 256 + ((g ^ (r & 7)) << 3)];
    }

    for (int z = 0; z < 3; ++z) {
        const u16* wz = w3 + z * (I_DIM * C_DIM);
        f32x16 acc[2] = {};
        #pragma unroll
        for (int ks = 0; ks < 16; ++ks) {
            #pragma unroll
            for (int f = 0; f < 2; ++f) {
                int irow = (2 * ip + f) * 32 + cl;
                bf16x8 bfr = *(const bf16x8*)(wz + (size_t)irow * C_DIM + ks * 16 + h * 8);
                acc[f] = __builtin_amdgcn_mfma_f32_32x32x16_bf16(afr[ks], bfr, acc[f], 0, 0, 0);
            }
        }
        if (z < 2) {
            float sc = (z == 0) ? TH_SCALE : 1.0f;
            // Ep as [n64][i 136pad]
            #pragma unroll
            for (int f = 0; f < 2; ++f) {
                int i = (2 * ip + f) * 32 + cl;
                #pragma unroll
                for (int r2 = 0; r2 < 4; ++r2)
                    #pragma unroll
                    for (int e = 0; e < 4; ++e) {
                        int n = mt * 32 + 8 * r2 + 4 * h + e;
                        Ep[n * 136 + i] = f2bf(acc[f][4 * r2 + e] * sc);
                    }
            }
            __syncthreads();
            u16* dst = (z == 0) ? theta : phiT;
            #pragma unroll
            for (int it = 0; it < 4; ++it) {
                int id = it * 256 + t;
                int n = id >> 4, l16 = id & 15;
                f32x4 vv = *(const f32x4*)&Ep[n * 136 + l16 * 8];
                *(f32x4*)(dst + ((size_t)(b * N_DIM) + n0 + n) * I_DIM + l16 * 8) = vv;
            }
            __syncthreads();
        } else {
            // Ep as [i128][n 72pad]
            #pragma unroll
            for (int f = 0; f < 2; ++f) {
                int i = (2 * ip + f) * 32 + cl;
                #pragma unroll
                for (int r2 = 0; r2 < 4; ++r2) {
                    u32 lo = pk2(acc[f][4 * r2 + 0], acc[f][4 * r2 + 1]);
                    u32 hi = pk2(acc[f][4 * r2 + 2], acc[f][4 * r2 + 3]);
                    int nb = mt * 32 + 8 * r2 + 4 * h;
                    *(u32*)&Ep[i * 72 + nb] = lo;
                    *(u32*)&Ep[i * 72 + nb + 2] = hi;
                }
            }
            __syncthreads();
            #pragma unroll
            for (int it = 0; it < 4; ++it) {
                int id = it * 256 + t;
                int i = id >> 3, l8 = id & 7;
                f32x4 vv = *(const f32x4*)&Ep[i * 72 + l8 * 8];
                *(f32x4*)(gT + ((size_t)(b * I_DIM) + i) * N_DIM + n0 + l8 * 8) = vv;
            }
        }
    }
}

// ---- 5: flash attention, 8 waves/block: wave-pairs split each 64-key chunk ----
// kh = w>>2 takes keys [kh*32, kh*32+32) of every chunk; O/lsum partials are
// summed through LDS in the epilogue (exact: no-max softmax partials add).
// Pipeline: raw s_barrier + s_waitcnt vmcnt(4) — prefetch loads stay in flight
// across the barrier; only the last chunk drains vmcnt(0).
// 16 waves/CU (2 blocks x 8 waves, LDS ~71KB, VGPR<=128 via launch_bounds).
__global__ __launch_bounds__(512, 4) void attn_kernel(const u16* __restrict__ theta,
                                                      const u16* __restrict__ phiT,
                                                      const u16* __restrict__ gT,
                                                      u16* __restrict__ ao0, u16* __restrict__ ao1,
                                                      float* __restrict__ l0, float* __restrict__ l1,
                                                      const float* __restrict__ pooled,
                                                      const float* __restrict__ fc1w,
                                                      const float* __restrict__ fc1b,
                                                      const float* __restrict__ fc2w,
                                                      const float* __restrict__ fc2b,
                                                      float* __restrict__ chw) {
    const int bid = blockIdx.x;
    const int b = bid & 7, mh = (bid >> 3) & 1, qt = bid >> 4;
    const int t = threadIdx.x, lane = t & 63, w = t >> 6;
    const int cl = lane & 31, h = lane >> 5;
    const int wt = w & 3, kh = w >> 2;
    const int qw = qt * 128 + wt * 32;   // wave q-base

    __shared__ __align__(16) u16 SM[34816];  // 68KB: K/V dbuf (64KB) | ep32 (68KB) | bf16 ep (32KB)
    __shared__ float lexs[8][32];
    __shared__ float sse[512];

    bf16x8 qf[8];
    {
        const u16* qp = theta + ((size_t)(b * N_DIM) + qw + cl) * I_DIM + h * 8;
        #pragma unroll
        for (int ks = 0; ks < 8; ++ks) qf[ks] = *(const bf16x8*)(qp + ks * 16);
    }

    const u16* kbase = phiT + (size_t)b * N_DIM * I_DIM + (size_t)(mh * 2048) * I_DIM;
    const u16* vbase = gT + (size_t)b * I_DIM * N_DIM + mh * 2048;
    const u16* kptr[2]; const u16* vptr[2];
    #pragma unroll
    for (int it = 0; it < 2; ++it) {
        int gi = (w * 2 + it) * 64 + lane;
        int kr = gi >> 4, kg = gi & 15;
        kptr[it] = kbase + (size_t)kr * I_DIM + ((kg ^ (kr & 7)) << 3);
        int vr = gi >> 3, vg = gi & 7;
        vptr[it] = vbase + (size_t)vr * N_DIM + ((vg ^ (vr & 7)) << 3);
    }

    auto issue = [&](int p) {
        u16* Kd = SM + p * 16384;
        u16* Vd = Kd + 8192;
        #pragma unroll
        for (int it = 0; it < 2; ++it) { async16(kptr[it], Kd + (w * 2 + it) * 512); kptr[it] += 64 * I_DIM; }
        #pragma unroll
        for (int it = 0; it < 2; ++it) { async16(vptr[it], Vd + (w * 2 + it) * 512); vptr[it] += 64; }
    };

    float lsum = 0.f;
    f32x16 O[4] = {};
    const int krow = kh * 32 + cl;
    const int kswz = krow & 7;

    issue(0);   // chunk 0 -> buf 0

    for (int mc = 0; mc < 32; ++mc) {
        const int p = mc & 1;
        // (A) all waves done computing chunk mc-1 -> buf 1-p is free to overwrite
        __asm__ volatile("s_barrier" ::: "memory");
        if (mc < 31) {
            issue(1 - p);   // prefetch chunk mc+1; stays in flight across barrier B
            __asm__ volatile("s_waitcnt vmcnt(4)" ::: "memory");   // own chunk-mc loads retired
        } else {
            __asm__ volatile("s_waitcnt vmcnt(0)" ::: "memory");
        }
        // (B) all waves' chunk-mc loads retired -> buf p fully populated
        __asm__ volatile("s_barrier" ::: "memory");

        const u16* Ks = SM + p * 16384;
        const u16* Vs = Ks + 8192;

        // S^T = K Q^T over this wave's 32-key half; theta pre-scaled so P = exp2(S)
        f32x16 S = {};
        __builtin_amdgcn_s_setprio(1);
        #pragma unroll
        for (int ks = 0; ks < 8; ++ks) {
            bf16x8 kf = *(const bf16x8*)&Ks[krow * 128 + (((2 * ks + h) ^ kswz) << 3)];
            S = __builtin_amdgcn_mfma_f32_32x32x16_bf16(kf, qf[ks], S, 0, 0, 0);
        }
        __builtin_amdgcn_s_setprio(0);

        u32 pk[4][2];
        #pragma unroll
        for (int r2 = 0; r2 < 4; ++r2) {
            float p0 = __builtin_amdgcn_exp2f(S[4 * r2 + 0]);
            float p1 = __builtin_amdgcn_exp2f(S[4 * r2 + 1]);
            float p2 = __builtin_amdgcn_exp2f(S[4 * r2 + 2]);
            float p3 = __builtin_amdgcn_exp2f(S[4 * r2 + 3]);
            lsum += (p0 + p1) + (p2 + p3);
            pk[r2][0] = pk2t(p0, p1);
            pk[r2][1] = pk2t(p2, p3);
        }

        // O += P V ; A-frag assembled via 2x v_permlane32_swap per k-slice
        __builtin_amdgcn_s_setprio(1);
        #pragma unroll
        for (int s = 0; s < 2; ++s) {
            u32 x0 = pk[2 * s][0], y0 = pk[2 * s + 1][0];
            u32 x1 = pk[2 * s][1], y1 = pk[2 * s + 1][1];
            plswap(x0, y0);
            plswap(x1, y1);
            BF8 A;
            A.u[0] = x0; A.u[1] = x1; A.u[2] = y0; A.u[3] = y1;
            const int g = 4 * kh + 2 * s + h;
            #pragma unroll
            for (int f = 0; f < 4; ++f) {
                int ir = f * 32 + cl;
                bf16x8 vf = *(const bf16x8*)&Vs[ir * 64 + ((g ^ (ir & 7)) << 3)];
                O[f] = __builtin_amdgcn_mfma_f32_32x32x16_bf16(A.v, vf, O[f], 0, 0, 0);
            }
        }
        __builtin_amdgcn_s_setprio(0);
    }

    // ---- epilogue: combine key-half partials across wave pairs ----
    {   // h-half lsum combine, in-register
        union { float f; u32 u; } a, b2;
        a.f = lsum; b2.f = lsum;
        plswap(a.u, b2.u);
        lsum = a.f + b2.f;
    }
    if (h == 0) lexs[w][cl] = lsum;
    __syncthreads();   // all K/V reads done (SM free) + lexs published

    float* ep32 = (float*)SM;                       // [tile4][lane64][pad 68] f32
    float* slot = ep32 + ((wt << 6) + lane) * 68;
    if (kh == 0) {
        #pragma unroll
        for (int f = 0; f < 4; ++f)
            #pragma unroll
            for (int r2 = 0; r2 < 4; ++r2) {
                f32x4 vv = {O[f][4 * r2 + 0], O[f][4 * r2 + 1], O[f][4 * r2 + 2], O[f][4 * r2 + 3]};
                *(f32x4*)(slot + f * 16 + r2 * 4) = vv;
            }
    }
    __syncthreads();

    u16* aop = (mh == 0) ? ao0 : ao1;
    float* lp = (mh == 0) ? l0 : l1;

    if (kh == 1) {
        if (h == 0) lp[(size_t)b * N_DIM + qw + cl] = lexs[wt][cl] + lexs[wt + 4][cl];
        float linv[16];
        #pragma unroll
        for (int r2 = 0; r2 < 4; ++r2) {
            f32x4 la = *(const f32x4*)&lexs[wt][8 * r2 + 4 * h];
            f32x4 lb = *(const f32x4*)&lexs[wt + 4][8 * r2 + 4 * h];
            #pragma unroll
            for (int e = 0; e < 4; ++e) linv[4 * r2 + e] = 1.f / (la[e] + lb[e]);
        }
        #pragma unroll
        for (int f = 0; f < 4; ++f)
            #pragma unroll
            for (int r2 = 0; r2 < 4; ++r2) {
                f32x4 pv = *(const f32x4*)(slot + f * 16 + r2 * 4);
                #pragma unroll
                for (int e = 0; e < 4; ++e)
                    O[f][4 * r2 + e] = (O[f][4 * r2 + e] + pv[e]) * linv[4 * r2 + e];
            }
    }
    __syncthreads();   // ep32 fully consumed before bf16 staging overwrites SM

    if (kh == 1) {
        u16* ep = SM + wt * 4096;   // [q32][i128] per tile, 8KB
        #pragma unroll
        for (int f = 0; f < 4; ++f)
            #pragma unroll
            for (int r2 = 0; r2 < 4; ++r2)
                #pragma unroll
                for (int e = 0; e < 4; ++e) {
                    int q = 8 * r2 + 4 * h + e;
                    ep[q * 128 + f * 32 + cl] = f2bf(O[f][4 * r2 + e]);
                }
        __asm__ volatile("s_waitcnt lgkmcnt(0)" ::: "memory");
        #pragma unroll
        for (int it = 0; it < 8; ++it) {
            int id = it * 64 + lane;
            int q = id >> 4, l16 = id & 15;
            f32x4 vv = *(const f32x4*)&ep[q * 128 + l16 * 8];
            *(f32x4*)(aop + ((size_t)(b * N_DIM) + qw + q) * I_DIM + l16 * 8) = vv;
        }
    }

    // ---- fused SE MLP (block 0 only; pooled complete since qkv finished) ----
    if (bid == 0) {
        const int sb = t >> 6;   // batch 0..7
        const int j = t & 63;    // hidden unit
        float d = 0.f;
        for (int c = 0; c < C_DIM; c += 4) {
            float4 pv = *(const float4*)(pooled + sb * C_DIM + c);
            float4 wv = *(const float4*)(fc1w + j * C_DIM + c);
            d += (pv.x * wv.x + pv.y * wv.y) + (pv.z * wv.z + pv.w * wv.w);
        }
        float a = fc1b[j] + d * (1.f / N_DIM);
        sse[sb * 64 + j] = a > 0.f ? a : 0.f;
        __syncthreads();
        #pragma unroll
        for (int r = 0; r < 4; ++r) {
            int c = j * 4 + r;
            float acc = fc2b[c];
            for (int k = 0; k < R_DIM; k += 4) {
                float4 wv = *(const float4*)(fc2w + c * 64 + k);
                acc += (sse[sb * 64 + k] * wv.x + sse[sb * 64 + k + 1] * wv.y)
                     + (sse[sb * 64 + k + 2] * wv.z + sse[sb * 64 + k + 3] * wv.w);
            }
            chw[sb * C_DIM + c] = 1.f / (1.f + __builtin_amdgcn_exp2f(-acc * 1.44269504089f));
        }
    }
}

// ---- 6: out projection + partial combine + BN stats ----
__global__ __launch_bounds__(256) void oproj_kernel(const u16* __restrict__ ao0,
                                                    const u16* __restrict__ ao1,
                                                    const float* __restrict__ l0,
                                                    const float* __restrict__ l1,
                                                    const u16* __restrict__ owb,
                                                    u16* __restrict__ out2,
                                                    float* __restrict__ bnsum,
                                                    float* __restrict__ bnsumsq) {
    const int bid = blockIdx.x;
    const int b = bid & 7, nt = bid >> 3;
    const int n0 = nt * 64;
    const int t = threadIdx.x, lane = t & 63, w = t >> 6;
    const int cl = lane & 31, h = lane >> 5;

    __shared__ u16 Ep[256 * 72];   // [c][n 72pad]
    __shared__ float lsum[C_DIM], lsq[C_DIM];
    lsum[t] = 0.f; lsq[t] = 0.f;
    __syncthreads();

    const int mt = w & 1;
    const int nn = n0 + mt * 32 + cl;
    float w0, w1;
    {
        float la = l0[(size_t)b * N_DIM + nn], lb = l1[(size_t)b * N_DIM + nn];
        float inv = 1.f / (la + lb);
        w0 = la * inv; w1 = lb * inv;
    }
    bf16x8 afr[8];
    {
        const u16* p0 = ao0 + ((size_t)(b * N_DIM) + nn) * I_DIM + h * 8;
        const u16* p1 = ao1 + ((size_t)(b * N_DIM) + nn) * I_DIM + h * 8;
        #pragma unroll
        for (int ks = 0; ks < 8; ++ks) {
            bf16x8 x0 = *(const bf16x8*)(p0 + ks * 16);
            bf16x8 x1 = *(const bf16x8*)(p1 + ks * 16);
            const u16* u0 = (const u16*)&x0;
            const u16* u1 = (const u16*)&x1;
            float c0 = w0 * bf2f(u0[0]) + w1 * bf2f(u1[0]);
            float c1 = w0 * bf2f(u0[1]) + w1 * bf2f(u1[1]);
            float c2 = w0 * bf2f(u0[2]) + w1 * bf2f(u1[2]);
            float c3 = w0 * bf2f(u0[3]) + w1 * bf2f(u1[3]);
            float c4 = w0 * bf2f(u0[4]) + w1 * bf2f(u1[4]);
            float c5 = w0 * bf2f(u0[5]) + w1 * bf2f(u1[5]);
            float c6 = w0 * bf2f(u0[6]) + w1 * bf2f(u1[6]);
            float c7 = w0 * bf2f(u0[7]) + w1 * bf2f(u1[7]);
            BF8 r;
            r.u[0] = pk2(c0, c1); r.u[1] = pk2(c2, c3);
            r.u[2] = pk2(c4, c5); r.u[3] = pk2(c6, c7);
            afr[ks] = r.v;
        }
    }

    f32x16 D[4] = {};
    #pragma unroll
    for (int ks = 0; ks < 8; ++ks) {
        #pragma unroll
        for (int j = 0; j < 4; ++j) {
            int cr = ((w >> 1) * 4 + j) * 32 + cl;
            bf16x8 bfr = *(const bf16x8*)(owb + (size_t)cr * I_DIM + ks * 16 + h * 8);
            D[j] = __builtin_amdgcn_mfma_f32_32x32x16_bf16(afr[ks], bfr, D[j], 0, 0, 0);
        }
    }

    #pragma unroll
    for (int j = 0; j < 4; ++j) {
        int c = ((w >> 1) * 4 + j) * 32 + cl;
        float s1 = 0.f, s2 = 0.f;
        #pragma unroll
        for (int r2 = 0; r2 < 4; ++r2) {
            float v0 = D[j][4 * r2 + 0], v1 = D[j][4 * r2 + 1];
            float v2 = D[j][4 * r2 + 2], v3 = D[j][4 * r2 + 3];
            s1 += (v0 + v1) + (v2 + v3);
            s2 += (v0 * v0 + v1 * v1) + (v2 * v2 + v3 * v3);
            int nb = mt * 32 + 8 * r2 + 4 * h;
            *(u32*)&Ep[c * 72 + nb] = pk2(v0, v1);
            *(u32*)&Ep[c * 72 + nb + 2] = pk2(v2, v3);
        }
        atomicAdd(&lsum[c], s1);
        atomicAdd(&lsq[c], s2);
    }
    __syncthreads();
    #pragma unroll
    for (int it = 0; it < 8; ++it) {
        int id = it * 256 + t;
        int c = id >> 3, l8 = id & 7;
        f32x4 vv = *(const f32x4*)&Ep[c * 72 + l8 * 8];
        *(f32x4*)(out2 + ((size_t)(b * C_DIM) + c) * N_DIM + n0 + l8 * 8) = vv;
    }
    atomicAdd(&bnsum[t], lsum[t]);
    atomicAdd(&bnsumsq[t], lsq[t]);
}

// ---- 7: BN normalize + SE scale + residual ----
__global__ void final_kernel(const float* __restrict__ x, const u16* __restrict__ out2,
                             const float* __restrict__ bnsum, const float* __restrict__ bnsumsq,
                             const float* __restrict__ gamma, const float* __restrict__ beta,
                             const float* __restrict__ chw, float* __restrict__ out) {
    int idx = blockIdx.x * 256 + threadIdx.x;
    int e = idx * 4;
    int b = e >> 20;
    int c = (e >> 12) & 255;
    float mean = bnsum[c] * (1.f / 32768.f);
    float var = bnsumsq[c] * (1.f / 32768.f) - mean * mean;
    float sc = gamma[c] * rsqrtf(var + 1e-5f);
    float sh = beta[c] - mean * sc;
    float cw = chw[b * C_DIM + c];
    ushort4 o16 = ((const ushort4*)out2)[idx];
    float4 xv = ((const float4*)x)[idx];
    float4 res;
    res.x = xv.x + (bf2f(o16.x) * sc + sh) * cw;
    res.y = xv.y + (bf2f(o16.y) * sc + sh) * cw;
    res.z = xv.z + (bf2f(o16.z) * sc + sh) * cw;
    res.w = xv.w + (bf2f(o16.w) * sc + sh) * cw;
    ((float4*)out)[idx] = res;
}

extern "C" void kernel_launch(void* const* d_in, const int* in_sizes, int n_in,
                              void* d_out, int out_size, void* d_ws, size_t ws_size,
                              hipStream_t stream) {
    const float* x   = (const float*)d_in[0];
    const float* tw  = (const float*)d_in[1];
    const float* pw  = (const float*)d_in[2];
    const float* gw  = (const float*)d_in[3];
    const float* ow  = (const float*)d_in[4];
    const float* gam = (const float*)d_in[5];
    const float* bet = (const float*)d_in[6];
    const float* f1w = (const float*)d_in[7];
    const float* f1b = (const float*)d_in[8];
    const float* f2w = (const float*)d_in[9];
    const float* f2b = (const float*)d_in[10];
    float* out = (float*)d_out;

    char* ws = (char*)d_ws;
    float* bnsum   = (float*)(ws + OFF_BNSUM);
    float* bnsumsq = (float*)(ws + OFF_BNSQ);
    float* pooled  = (float*)(ws + OFF_POOL);
    float* chw     = (float*)(ws + OFF_CHW);
    u16*   w3      = (u16*)(ws + OFF_W3);
    u16*   owb     = (u16*)(ws + OFF_OWB);
    u16*   ao0     = (u16*)(ws + OFF_AO0);
    u16*   ao1     = (u16*)(ws + OFF_AO1);
    u16*   theta   = (u16*)(ws + OFF_THETA);
    u16*   phiT    = (u16*)(ws + OFF_PHIT);
    u16*   gT      = (u16*)(ws + OFF_GT);
    float* l0      = (float*)(ws + OFF_L0);
    float* l1      = (float*)(ws + OFF_L1);
    u16*   out2    = (u16*)(ws + OFF_OUT2);

    prep_kernel<<<384, 256, 0, stream>>>(tw, pw, gw, ow, w3, owb, bnsum, pooled);
    qkv_kernel<<<512, 256, 0, stream>>>(x, w3, theta, phiT, gT, pooled);
    attn_kernel<<<512, 512, 0, stream>>>(theta, phiT, gT, ao0, ao1, l0, l1,
                                         pooled, f1w, f1b, f2w, f2b, chw);
    oproj_kernel<<<512, 256, 0, stream>>>(ao0, ao1, l0, l1, owb, out2, bnsum, bnsumsq);
    final_kernel<<<8192, 256, 0, stream>>>(x, out2, bnsum, bnsumsq, gam, bet, chw, out);
}

// Round 2
// 299.251 us; speedup vs baseline: 1.1075x; 1.1075x over previous
//
#include <hip/hip_runtime.h>

#define B_DIM 8
#define C_DIM 256
#define I_DIM 128
#define N_DIM 4096
#define R_DIM 64

typedef unsigned short u16;
typedef unsigned int u32;
typedef __attribute__((ext_vector_type(8))) __bf16 bf16x8;
typedef __attribute__((ext_vector_type(4))) float f32x4;
typedef __attribute__((ext_vector_type(16))) float f32x16;

union BF8 { u32 u[4]; bf16x8 v; };

__device__ __forceinline__ u16 f2bf(float f) {
    union { float f; u32 u; } v; v.f = f;
    u32 r = v.u + 0x7FFFu + ((v.u >> 16) & 1u);
    return (u16)(r >> 16);
}
__device__ __forceinline__ float bf2f(u16 h) {
    union { u32 u; float f; } v; v.u = (u32)h << 16; return v.f;
}
__device__ __forceinline__ u32 pk2(float a, float b) {
    return (u32)f2bf(a) | ((u32)f2bf(b) << 16);
}
// truncating bf16 pack: [b.hi16 | a.hi16] in ONE v_perm_b32
__device__ __forceinline__ u32 pk2t(float a, float b) {
    union { float f; u32 u; } ua, ub; ua.f = a; ub.f = b;
    return __builtin_amdgcn_perm(ub.u, ua.u, 0x07060302u);
}
__device__ __forceinline__ void async16(const u16* g, u16* l) {
    __builtin_amdgcn_global_load_lds((const __attribute__((address_space(1))) void*)g,
                                     (__attribute__((address_space(3))) void*)l, 16, 0, 0);
}
// v_permlane32_swap: a' = [a.lo32 | b.lo32], b' = [a.hi32 | b.hi32]
__device__ __forceinline__ void plswap(u32& a, u32& b) {
    __asm__("v_permlane32_swap_b32 %0, %1" : "+v"(a), "+v"(b));
}

// log2(e)/sqrt(128), folded into theta at projection time
#define TH_SCALE 0.1275204890136f

// ---- workspace layout (bytes) ----
static constexpr size_t OFF_BNSUM = 0;
static constexpr size_t OFF_BNSQ  = 1024;
static constexpr size_t OFF_POOL  = 2048;
static constexpr size_t OFF_CHW   = 10240;
static constexpr size_t OFF_W3    = 18432;                  // 3*128*256 bf16
static constexpr size_t OFF_OWB   = 215040;                 // 256*128 bf16
static constexpr size_t OFF_AO0   = 280576;                 // [B,N,I] bf16 partial 0
static constexpr size_t OFF_AO1   = OFF_AO0 + 8388608;      // partial 1
static constexpr size_t OFF_THETA = OFF_AO1 + 8388608;      // [B,N,I] bf16 (pre-scaled)
static constexpr size_t OFF_PHIT  = OFF_THETA + 8388608;
static constexpr size_t OFF_GT    = OFF_PHIT + 8388608;     // [B,I,N] bf16
static constexpr size_t OFF_L0    = OFF_GT + 8388608;       // [B,N] f32
static constexpr size_t OFF_L1    = OFF_L0 + 131072;
static constexpr size_t OFF_OUT2  = OFF_L1 + 131072;        // [B,C,N] bf16

// ---- 1: weight convert + zero accumulators ----
__global__ void prep_kernel(const float* __restrict__ tw, const float* __restrict__ pw,
                            const float* __restrict__ gw, const float* __restrict__ ow,
                            u16* __restrict__ w3, u16* __restrict__ owb,
                            float* __restrict__ bnzero, float* __restrict__ pooled) {
    int idx = blockIdx.x * 256 + threadIdx.x;
    if (idx < 512) bnzero[idx] = 0.f;
    if (idx < 2048) pooled[idx] = 0.f;
    if (idx < 3 * 32768) {
        const float* src = idx < 32768 ? tw : (idx < 65536 ? pw : gw);
        w3[idx] = f2bf(src[idx & 32767]);
    }
    if (idx < 32768) owb[idx] = f2bf(ow[idx]);
}

// ---- 4: fused QKV projection (direct from x, 32x32x16 MFMA) + SE pooling ----
__global__ __launch_bounds__(256) void qkv_kernel(const float* __restrict__ x,
                                                  const u16* __restrict__ w3,
                                                  u16* __restrict__ theta,
                                                  u16* __restrict__ phiT,
                                                  u16* __restrict__ gT,
                                                  float* __restrict__ pooled) {
    const int bid = blockIdx.x;
    const int b = bid & 7, nt = bid >> 3;
    const int n0 = nt * 64;
    const int t = threadIdx.x, lane = t & 63, w = t >> 6;
    const int cl = lane & 31, h = lane >> 5;

    __shared__ u16 As[64 * 256];   // [n][c] bf16, 16B-granule swizzled ^(n&7)
    __shared__ u16 Ep[128 * 72];   // epilogue buffer

    {   // stage x[b, :, n0:n0+64] -> As (transposed to [n][c]); fused SE pooling
        const float* xb = x + ((size_t)b * C_DIM) * N_DIM + n0;
        for (int it = 0; it < 16; ++it) {
            int id = it * 256 + t;
            int c = id >> 4, l16 = id & 15;
            float4 v = *(const float4*)(xb + (size_t)c * N_DIM + l16 * 4);
            int g = c >> 3, co = c & 7;
            float vv[4] = {v.x, v.y, v.z, v.w};
            #pragma unroll
            for (int k = 0; k < 4; ++k) {
                int n = l16 * 4 + k;
                As[n * 256 + ((g ^ (n & 7)) << 3) + co] = f2bf(vv[k]);
            }
            float s = (v.x + v.y) + (v.z + v.w);
            s += __shfl_xor(s, 1); s += __shfl_xor(s, 2);
            s += __shfl_xor(s, 4); s += __shfl_xor(s, 8);
            if ((t & 15) == 0) atomicAdd(&pooled[b * C_DIM + c], s);
        }
    }
    __syncthreads();

    const int mt = w & 1;    // n-tile
    const int ip = w >> 1;   // i-pair
    bf16x8 afr[16];
    #pragma unroll
    for (int ks = 0; ks < 16; ++ks) {
        int r = mt * 32 + cl;
        int g = 2 * ks + h;
        afr[ks] = *(const bf16x8*)&As[r * 256 + ((g ^ (r & 7)) << 3)];
    }

    for (int z = 0; z < 3; ++z) {
        const u16* wz = w3 + z * (I_DIM * C_DIM);
        f32x16 acc[2] = {};
        #pragma unroll
        for (int ks = 0; ks < 16; ++ks) {
            #pragma unroll
            for (int f = 0; f < 2; ++f) {
                int irow = (2 * ip + f) * 32 + cl;
                bf16x8 bfr = *(const bf16x8*)(wz + (size_t)irow * C_DIM + ks * 16 + h * 8);
                acc[f] = __builtin_amdgcn_mfma_f32_32x32x16_bf16(afr[ks], bfr, acc[f], 0, 0, 0);
            }
        }
        if (z < 2) {
            float sc = (z == 0) ? TH_SCALE : 1.0f;
            // Ep as [n64][i 136pad]
            #pragma unroll
            for (int f = 0; f < 2; ++f) {
                int i = (2 * ip + f) * 32 + cl;
                #pragma unroll
                for (int r2 = 0; r2 < 4; ++r2)
                    #pragma unroll
                    for (int e = 0; e < 4; ++e) {
                        int n = mt * 32 + 8 * r2 + 4 * h + e;
                        Ep[n * 136 + i] = f2bf(acc[f][4 * r2 + e] * sc);
                    }
            }
            __syncthreads();
            u16* dst = (z == 0) ? theta : phiT;
            #pragma unroll
            for (int it = 0; it < 4; ++it) {
                int id = it * 256 + t;
                int n = id >> 4, l16 = id & 15;
                f32x4 vv = *(const f32x4*)&Ep[n * 136 + l16 * 8];
                *(f32x4*)(dst + ((size_t)(b * N_DIM) + n0 + n) * I_DIM + l16 * 8) = vv;
            }
            __syncthreads();
        } else {
            // Ep as [i128][n 72pad]
            #pragma unroll
            for (int f = 0; f < 2; ++f) {
                int i = (2 * ip + f) * 32 + cl;
                #pragma unroll
                for (int r2 = 0; r2 < 4; ++r2) {
                    u32 lo = pk2(acc[f][4 * r2 + 0], acc[f][4 * r2 + 1]);
                    u32 hi = pk2(acc[f][4 * r2 + 2], acc[f][4 * r2 + 3]);
                    int nb = mt * 32 + 8 * r2 + 4 * h;
                    *(u32*)&Ep[i * 72 + nb] = lo;
                    *(u32*)&Ep[i * 72 + nb + 2] = hi;
                }
            }
            __syncthreads();
            #pragma unroll
            for (int it = 0; it < 4; ++it) {
                int id = it * 256 + t;
                int i = id >> 3, l8 = id & 7;
                f32x4 vv = *(const f32x4*)&Ep[i * 72 + l8 * 8];
                *(f32x4*)(gT + ((size_t)(b * I_DIM) + i) * N_DIM + n0 + l8 * 8) = vv;
            }
        }
    }
}

// ---- 5: flash attention, 8 waves/block: wave-pairs split each 64-key chunk ----
// kh = w>>2 takes keys [kh*32, kh*32+32) of every chunk; O/lsum partials are
// summed through LDS in the epilogue (exact: no-max softmax partials add).
// Pipeline: raw s_barrier + s_waitcnt vmcnt(4) — prefetch loads stay in flight
// across the barrier; only the last chunk drains vmcnt(0).
// __launch_bounds__(512, 2): 2 blocks/CU (16 waves) -> VGPR cap 128, no spill.
// (Round-1's (512,4) forced a 64-VGPR cap -> 33MB of scratch spill traffic.)
__global__ __launch_bounds__(512, 2) void attn_kernel(const u16* __restrict__ theta,
                                                      const u16* __restrict__ phiT,
                                                      const u16* __restrict__ gT,
                                                      u16* __restrict__ ao0, u16* __restrict__ ao1,
                                                      float* __restrict__ l0, float* __restrict__ l1,
                                                      const float* __restrict__ pooled,
                                                      const float* __restrict__ fc1w,
                                                      const float* __restrict__ fc1b,
                                                      const float* __restrict__ fc2w,
                                                      const float* __restrict__ fc2b,
                                                      float* __restrict__ chw) {
    const int bid = blockIdx.x;
    const int b = bid & 7, mh = (bid >> 3) & 1, qt = bid >> 4;
    const int t = threadIdx.x, lane = t & 63, w = t >> 6;
    const int cl = lane & 31, h = lane >> 5;
    const int wt = w & 3, kh = w >> 2;
    const int qw = qt * 128 + wt * 32;   // wave q-base

    __shared__ __align__(16) u16 SM[34816];  // 68KB: K/V dbuf (64KB) | ep32 (68KB) | bf16 ep (32KB)
    __shared__ float lexs[8][32];
    __shared__ float sse[512];

    bf16x8 qf[8];
    {
        const u16* qp = theta + ((size_t)(b * N_DIM) + qw + cl) * I_DIM + h * 8;
        #pragma unroll
        for (int ks = 0; ks < 8; ++ks) qf[ks] = *(const bf16x8*)(qp + ks * 16);
    }

    const u16* kbase = phiT + (size_t)b * N_DIM * I_DIM + (size_t)(mh * 2048) * I_DIM;
    const u16* vbase = gT + (size_t)b * I_DIM * N_DIM + mh * 2048;
    const u16* kptr[2]; const u16* vptr[2];
    #pragma unroll
    for (int it = 0; it < 2; ++it) {
        int gi = (w * 2 + it) * 64 + lane;
        int kr = gi >> 4, kg = gi & 15;
        kptr[it] = kbase + (size_t)kr * I_DIM + ((kg ^ (kr & 7)) << 3);
        int vr = gi >> 3, vg = gi & 7;
        vptr[it] = vbase + (size_t)vr * N_DIM + ((vg ^ (vr & 7)) << 3);
    }

    auto issue = [&](int p) {
        u16* Kd = SM + p * 16384;
        u16* Vd = Kd + 8192;
        #pragma unroll
        for (int it = 0; it < 2; ++it) { async16(kptr[it], Kd + (w * 2 + it) * 512); kptr[it] += 64 * I_DIM; }
        #pragma unroll
        for (int it = 0; it < 2; ++it) { async16(vptr[it], Vd + (w * 2 + it) * 512); vptr[it] += 64; }
    };

    float lsum = 0.f;
    f32x16 O[4] = {};
    const int krow = kh * 32 + cl;
    const int kswz = krow & 7;

    issue(0);   // chunk 0 -> buf 0

    for (int mc = 0; mc < 32; ++mc) {
        const int p = mc & 1;
        // (A) all waves done computing chunk mc-1 -> buf 1-p is free to overwrite
        __asm__ volatile("s_barrier" ::: "memory");
        if (mc < 31) {
            issue(1 - p);   // prefetch chunk mc+1; stays in flight across barrier B
            __asm__ volatile("s_waitcnt vmcnt(4)" ::: "memory");   // own chunk-mc loads retired
        } else {
            __asm__ volatile("s_waitcnt vmcnt(0)" ::: "memory");
        }
        // (B) all waves' chunk-mc loads retired -> buf p fully populated
        __asm__ volatile("s_barrier" ::: "memory");

        const u16* Ks = SM + p * 16384;
        const u16* Vs = Ks + 8192;

        // S^T = K Q^T over this wave's 32-key half; theta pre-scaled so P = exp2(S)
        f32x16 S = {};
        __builtin_amdgcn_s_setprio(1);
        #pragma unroll
        for (int ks = 0; ks < 8; ++ks) {
            bf16x8 kf = *(const bf16x8*)&Ks[krow * 128 + (((2 * ks + h) ^ kswz) << 3)];
            S = __builtin_amdgcn_mfma_f32_32x32x16_bf16(kf, qf[ks], S, 0, 0, 0);
        }
        __builtin_amdgcn_s_setprio(0);

        u32 pk[4][2];
        #pragma unroll
        for (int r2 = 0; r2 < 4; ++r2) {
            float p0 = __builtin_amdgcn_exp2f(S[4 * r2 + 0]);
            float p1 = __builtin_amdgcn_exp2f(S[4 * r2 + 1]);
            float p2 = __builtin_amdgcn_exp2f(S[4 * r2 + 2]);
            float p3 = __builtin_amdgcn_exp2f(S[4 * r2 + 3]);
            lsum += (p0 + p1) + (p2 + p3);
            pk[r2][0] = pk2t(p0, p1);
            pk[r2][1] = pk2t(p2, p3);
        }

        // O += P V ; A-frag assembled via 2x v_permlane32_swap per k-slice
        __builtin_amdgcn_s_setprio(1);
        #pragma unroll
        for (int s = 0; s < 2; ++s) {
            u32 x0 = pk[2 * s][0], y0 = pk[2 * s + 1][0];
            u32 x1 = pk[2 * s][1], y1 = pk[2 * s + 1][1];
            plswap(x0, y0);
            plswap(x1, y1);
            BF8 A;
            A.u[0] = x0; A.u[1] = x1; A.u[2] = y0; A.u[3] = y1;
            const int g = 4 * kh + 2 * s + h;
            #pragma unroll
            for (int f = 0; f < 4; ++f) {
                int ir = f * 32 + cl;
                bf16x8 vf = *(const bf16x8*)&Vs[ir * 64 + ((g ^ (ir & 7)) << 3)];
                O[f] = __builtin_amdgcn_mfma_f32_32x32x16_bf16(A.v, vf, O[f], 0, 0, 0);
            }
        }
        __builtin_amdgcn_s_setprio(0);
    }

    // ---- epilogue: combine key-half partials across wave pairs ----
    {   // h-half lsum combine, in-register
        union { float f; u32 u; } a, b2;
        a.f = lsum; b2.f = lsum;
        plswap(a.u, b2.u);
        lsum = a.f + b2.f;
    }
    if (h == 0) lexs[w][cl] = lsum;
    __syncthreads();   // all K/V reads done (SM free) + lexs published

    float* ep32 = (float*)SM;                       // [tile4][lane64][pad 68] f32
    float* slot = ep32 + ((wt << 6) + lane) * 68;
    if (kh == 0) {
        #pragma unroll
        for (int f = 0; f < 4; ++f)
            #pragma unroll
            for (int r2 = 0; r2 < 4; ++r2) {
                f32x4 vv = {O[f][4 * r2 + 0], O[f][4 * r2 + 1], O[f][4 * r2 + 2], O[f][4 * r2 + 3]};
                *(f32x4*)(slot + f * 16 + r2 * 4) = vv;
            }
    }
    __syncthreads();

    u16* aop = (mh == 0) ? ao0 : ao1;
    float* lp = (mh == 0) ? l0 : l1;

    if (kh == 1) {
        if (h == 0) lp[(size_t)b * N_DIM + qw + cl] = lexs[wt][cl] + lexs[wt + 4][cl];
        float linv[16];
        #pragma unroll
        for (int r2 = 0; r2 < 4; ++r2) {
            f32x4 la = *(const f32x4*)&lexs[wt][8 * r2 + 4 * h];
            f32x4 lb = *(const f32x4*)&lexs[wt + 4][8 * r2 + 4 * h];
            #pragma unroll
            for (int e = 0; e < 4; ++e) linv[4 * r2 + e] = 1.f / (la[e] + lb[e]);
        }
        #pragma unroll
        for (int f = 0; f < 4; ++f)
            #pragma unroll
            for (int r2 = 0; r2 < 4; ++r2) {
                f32x4 pv = *(const f32x4*)(slot + f * 16 + r2 * 4);
                #pragma unroll
                for (int e = 0; e < 4; ++e)
                    O[f][4 * r2 + e] = (O[f][4 * r2 + e] + pv[e]) * linv[4 * r2 + e];
            }
    }
    __syncthreads();   // ep32 fully consumed before bf16 staging overwrites SM

    if (kh == 1) {
        u16* ep = SM + wt * 4096;   // [q32][i128] per tile, 8KB
        #pragma unroll
        for (int f = 0; f < 4; ++f)
            #pragma unroll
            for (int r2 = 0; r2 < 4; ++r2)
                #pragma unroll
                for (int e = 0; e < 4; ++e) {
                    int q = 8 * r2 + 4 * h + e;
                    ep[q * 128 + f * 32 + cl] = f2bf(O[f][4 * r2 + e]);
                }
        __asm__ volatile("s_waitcnt lgkmcnt(0)" ::: "memory");
        #pragma unroll
        for (int it = 0; it < 8; ++it) {
            int id = it * 64 + lane;
            int q = id >> 4, l16 = id & 15;
            f32x4 vv = *(const f32x4*)&ep[q * 128 + l16 * 8];
            *(f32x4*)(aop + ((size_t)(b * N_DIM) + qw + q) * I_DIM + l16 * 8) = vv;
        }
    }

    // ---- fused SE MLP (block 0 only; pooled complete since qkv finished) ----
    if (bid == 0) {
        const int sb = t >> 6;   // batch 0..7
        const int j = t & 63;    // hidden unit
        float d = 0.f;
        for (int c = 0; c < C_DIM; c += 4) {
            float4 pv = *(const float4*)(pooled + sb * C_DIM + c);
            float4 wv = *(const float4*)(fc1w + j * C_DIM + c);
            d += (pv.x * wv.x + pv.y * wv.y) + (pv.z * wv.z + pv.w * wv.w);
        }
        float a = fc1b[j] + d * (1.f / N_DIM);
        sse[sb * 64 + j] = a > 0.f ? a : 0.f;
        __syncthreads();
        #pragma unroll
        for (int r = 0; r < 4; ++r) {
            int c = j * 4 + r;
            float acc = fc2b[c];
            for (int k = 0; k < R_DIM; k += 4) {
                float4 wv = *(const float4*)(fc2w + c * 64 + k);
                acc += (sse[sb * 64 + k] * wv.x + sse[sb * 64 + k + 1] * wv.y)
                     + (sse[sb * 64 + k + 2] * wv.z + sse[sb * 64 + k + 3] * wv.w);
            }
            chw[sb * C_DIM + c] = 1.f / (1.f + __builtin_amdgcn_exp2f(-acc * 1.44269504089f));
        }
    }
}

// ---- 6: out projection + partial combine + BN stats ----
__global__ __launch_bounds__(256) void oproj_kernel(const u16* __restrict__ ao0,
                                                    const u16* __restrict__ ao1,
                                                    const float* __restrict__ l0,
                                                    const float* __restrict__ l1,
                                                    const u16* __restrict__ owb,
                                                    u16* __restrict__ out2,
                                                    float* __restrict__ bnsum,
                                                    float* __restrict__ bnsumsq) {
    const int bid = blockIdx.x;
    const int b = bid & 7, nt = bid >> 3;
    const int n0 = nt * 64;
    const int t = threadIdx.x, lane = t & 63, w = t >> 6;
    const int cl = lane & 31, h = lane >> 5;

    __shared__ u16 Ep[256 * 72];   // [c][n 72pad]
    __shared__ float lsum[C_DIM], lsq[C_DIM];
    lsum[t] = 0.f; lsq[t] = 0.f;
    __syncthreads();

    const int mt = w & 1;
    const int nn = n0 + mt * 32 + cl;
    float w0, w1;
    {
        float la = l0[(size_t)b * N_DIM + nn], lb = l1[(size_t)b * N_DIM + nn];
        float inv = 1.f / (la + lb);
        w0 = la * inv; w1 = lb * inv;
    }
    bf16x8 afr[8];
    {
        const u16* p0 = ao0 + ((size_t)(b * N_DIM) + nn) * I_DIM + h * 8;
        const u16* p1 = ao1 + ((size_t)(b * N_DIM) + nn) * I_DIM + h * 8;
        #pragma unroll
        for (int ks = 0; ks < 8; ++ks) {
            bf16x8 x0 = *(const bf16x8*)(p0 + ks * 16);
            bf16x8 x1 = *(const bf16x8*)(p1 + ks * 16);
            const u16* u0 = (const u16*)&x0;
            const u16* u1 = (const u16*)&x1;
            float c0 = w0 * bf2f(u0[0]) + w1 * bf2f(u1[0]);
            float c1 = w0 * bf2f(u0[1]) + w1 * bf2f(u1[1]);
            float c2 = w0 * bf2f(u0[2]) + w1 * bf2f(u1[2]);
            float c3 = w0 * bf2f(u0[3]) + w1 * bf2f(u1[3]);
            float c4 = w0 * bf2f(u0[4]) + w1 * bf2f(u1[4]);
            float c5 = w0 * bf2f(u0[5]) + w1 * bf2f(u1[5]);
            float c6 = w0 * bf2f(u0[6]) + w1 * bf2f(u1[6]);
            float c7 = w0 * bf2f(u0[7]) + w1 * bf2f(u1[7]);
            BF8 r;
            r.u[0] = pk2(c0, c1); r.u[1] = pk2(c2, c3);
            r.u[2] = pk2(c4, c5); r.u[3] = pk2(c6, c7);
            afr[ks] = r.v;
        }
    }

    f32x16 D[4] = {};
    #pragma unroll
    for (int ks = 0; ks < 8; ++ks) {
        #pragma unroll
        for (int j = 0; j < 4; ++j) {
            int cr = ((w >> 1) * 4 + j) * 32 + cl;
            bf16x8 bfr = *(const bf16x8*)(owb + (size_t)cr * I_DIM + ks * 16 + h * 8);
            D[j] = __builtin_amdgcn_mfma_f32_32x32x16_bf16(afr[ks], bfr, D[j], 0, 0, 0);
        }
    }

    #pragma unroll
    for (int j = 0; j < 4; ++j) {
        int c = ((w >> 1) * 4 + j) * 32 + cl;
        float s1 = 0.f, s2 = 0.f;
        #pragma unroll
        for (int r2 = 0; r2 < 4; ++r2) {
            float v0 = D[j][4 * r2 + 0], v1 = D[j][4 * r2 + 1];
            float v2 = D[j][4 * r2 + 2], v3 = D[j][4 * r2 + 3];
            s1 += (v0 + v1) + (v2 + v3);
            s2 += (v0 * v0 + v1 * v1) + (v2 * v2 + v3 * v3);
            int nb = mt * 32 + 8 * r2 + 4 * h;
            *(u32*)&Ep[c * 72 + nb] = pk2(v0, v1);
            *(u32*)&Ep[c * 72 + nb + 2] = pk2(v2, v3);
        }
        atomicAdd(&lsum[c], s1);
        atomicAdd(&lsq[c], s2);
    }
    __syncthreads();
    #pragma unroll
    for (int it = 0; it < 8; ++it) {
        int id = it * 256 + t;
        int c = id >> 3, l8 = id & 7;
        f32x4 vv = *(const f32x4*)&Ep[c * 72 + l8 * 8];
        *(f32x4*)(out2 + ((size_t)(b * C_DIM) + c) * N_DIM + n0 + l8 * 8) = vv;
    }
    atomicAdd(&bnsum[t], lsum[t]);
    atomicAdd(&bnsumsq[t], lsq[t]);
}

// ---- 7: BN normalize + SE scale + residual ----
__global__ void final_kernel(const float* __restrict__ x, const u16* __restrict__ out2,
                             const float* __restrict__ bnsum, const float* __restrict__ bnsumsq,
                             const float* __restrict__ gamma, const float* __restrict__ beta,
                             const float* __restrict__ chw, float* __restrict__ out) {
    int idx = blockIdx.x * 256 + threadIdx.x;
    int e = idx * 4;
    int b = e >> 20;
    int c = (e >> 12) & 255;
    float mean = bnsum[c] * (1.f / 32768.f);
    float var = bnsumsq[c] * (1.f / 32768.f) - mean * mean;
    float sc = gamma[c] * rsqrtf(var + 1e-5f);
    float sh = beta[c] - mean * sc;
    float cw = chw[b * C_DIM + c];
    ushort4 o16 = ((const ushort4*)out2)[idx];
    float4 xv = ((const float4*)x)[idx];
    float4 res;
    res.x = xv.x + (bf2f(o16.x) * sc + sh) * cw;
    res.y = xv.y + (bf2f(o16.y) * sc + sh) * cw;
    res.z = xv.z + (bf2f(o16.z) * sc + sh) * cw;
    res.w = xv.w + (bf2f(o16.w) * sc + sh) * cw;
    ((float4*)out)[idx] = res;
}

extern "C" void kernel_launch(void* const* d_in, const int* in_sizes, int n_in,
                              void* d_out, int out_size, void* d_ws, size_t ws_size,
                              hipStream_t stream) {
    const float* x   = (const float*)d_in[0];
    const float* tw  = (const float*)d_in[1];
    const float* pw  = (const float*)d_in[2];
    const float* gw  = (const float*)d_in[3];
    const float* ow  = (const float*)d_in[4];
    const float* gam = (const float*)d_in[5];
    const float* bet = (const float*)d_in[6];
    const float* f1w = (const float*)d_in[7];
    const float* f1b = (const float*)d_in[8];
    const float* f2w = (const float*)d_in[9];
    const float* f2b = (const float*)d_in[10];
    float* out = (float*)d_out;

    char* ws = (char*)d_ws;
    float* bnsum   = (float*)(ws + OFF_BNSUM);
    float* bnsumsq = (float*)(ws + OFF_BNSQ);
    float* pooled  = (float*)(ws + OFF_POOL);
    float* chw     = (float*)(ws + OFF_CHW);
    u16*   w3      = (u16*)(ws + OFF_W3);
    u16*   owb     = (u16*)(ws + OFF_OWB);
    u16*   ao0     = (u16*)(ws + OFF_AO0);
    u16*   ao1     = (u16*)(ws + OFF_AO1);
    u16*   theta   = (u16*)(ws + OFF_THETA);
    u16*   phiT    = (u16*)(ws + OFF_PHIT);
    u16*   gT      = (u16*)(ws + OFF_GT);
    float* l0      = (float*)(ws + OFF_L0);
    float* l1      = (float*)(ws + OFF_L1);
    u16*   out2    = (u16*)(ws + OFF_OUT2);

    prep_kernel<<<384, 256, 0, stream>>>(tw, pw, gw, ow, w3, owb, bnsum, pooled);
    qkv_kernel<<<512, 256, 0, stream>>>(x, w3, theta, phiT, gT, pooled);
    attn_kernel<<<512, 512, 0, stream>>>(theta, phiT, gT, ao0, ao1, l0, l1,
                                         pooled, f1w, f1b, f2w, f2b, chw);
    oproj_kernel<<<512, 256, 0, stream>>>(ao0, ao1, l0, l1, owb, out2, bnsum, bnsumsq);
    final_kernel<<<8192, 256, 0, stream>>>(x, out2, bnsum, bnsumsq, gam, bet, chw, out);
}

// Round 3
// 298.308 us; speedup vs baseline: 1.1110x; 1.0032x over previous
//
#include <hip/hip_runtime.h>

#define B_DIM 8
#define C_DIM 256
#define I_DIM 128
#define N_DIM 4096
#define R_DIM 64

typedef unsigned short u16;
typedef unsigned int u32;
typedef __attribute__((ext_vector_type(8))) __bf16 bf16x8;
typedef __attribute__((ext_vector_type(4))) float f32x4;
typedef __attribute__((ext_vector_type(16))) float f32x16;

union BF8 { u32 u[4]; bf16x8 v; };

__device__ __forceinline__ u16 f2bf(float f) {
    union { float f; u32 u; } v; v.f = f;
    u32 r = v.u + 0x7FFFu + ((v.u >> 16) & 1u);
    return (u16)(r >> 16);
}
__device__ __forceinline__ float bf2f(u16 h) {
    union { u32 u; float f; } v; v.u = (u32)h << 16; return v.f;
}
__device__ __forceinline__ u32 pk2(float a, float b) {
    return (u32)f2bf(a) | ((u32)f2bf(b) << 16);
}
// truncating bf16 pack: [b.hi16 | a.hi16] in ONE v_perm_b32
__device__ __forceinline__ u32 pk2t(float a, float b) {
    union { float f; u32 u; } ua, ub; ua.f = a; ub.f = b;
    return __builtin_amdgcn_perm(ub.u, ua.u, 0x07060302u);
}
__device__ __forceinline__ void async16(const u16* g, u16* l) {
    __builtin_amdgcn_global_load_lds((const __attribute__((address_space(1))) void*)g,
                                     (__attribute__((address_space(3))) void*)l, 16, 0, 0);
}
// v_permlane32_swap: a' = [a.lo32 | b.lo32], b' = [a.hi32 | b.hi32]
__device__ __forceinline__ void plswap(u32& a, u32& b) {
    __asm__("v_permlane32_swap_b32 %0, %1" : "+v"(a), "+v"(b));
}

// log2(e)/sqrt(128), folded into theta at projection time
#define TH_SCALE 0.1275204890136f

// ---- workspace layout (bytes) ----
static constexpr size_t OFF_BNSUM = 0;
static constexpr size_t OFF_BNSQ  = 1024;
static constexpr size_t OFF_POOL  = 2048;
static constexpr size_t OFF_CHW   = 10240;
static constexpr size_t OFF_W3    = 18432;                  // 3*128*256 bf16
static constexpr size_t OFF_OWB   = 215040;                 // 256*128 bf16
static constexpr size_t OFF_AO0   = 280576;                 // [B,N,I] bf16 partial 0
static constexpr size_t OFF_AO1   = OFF_AO0 + 8388608;      // partial 1
static constexpr size_t OFF_THETA = OFF_AO1 + 8388608;      // [B,N,I] bf16 (pre-scaled)
static constexpr size_t OFF_PHIT  = OFF_THETA + 8388608;
static constexpr size_t OFF_GT    = OFF_PHIT + 8388608;     // [B,I,N] bf16
static constexpr size_t OFF_L0    = OFF_GT + 8388608;       // [B,N] f32
static constexpr size_t OFF_L1    = OFF_L0 + 131072;
static constexpr size_t OFF_OUT2  = OFF_L1 + 131072;        // [B,C,N] bf16

// ---- 1: weight convert + zero accumulators ----
__global__ void prep_kernel(const float* __restrict__ tw, const float* __restrict__ pw,
                            const float* __restrict__ gw, const float* __restrict__ ow,
                            u16* __restrict__ w3, u16* __restrict__ owb,
                            float* __restrict__ bnzero, float* __restrict__ pooled) {
    int idx = blockIdx.x * 256 + threadIdx.x;
    if (idx < 512) bnzero[idx] = 0.f;
    if (idx < 2048) pooled[idx] = 0.f;
    if (idx < 3 * 32768) {
        const float* src = idx < 32768 ? tw : (idx < 65536 ? pw : gw);
        w3[idx] = f2bf(src[idx & 32767]);
    }
    if (idx < 32768) owb[idx] = f2bf(ow[idx]);
}

// ---- 4: fused QKV projection (direct from x, 32x32x16 MFMA) + SE pooling ----
__global__ __launch_bounds__(256) void qkv_kernel(const float* __restrict__ x,
                                                  const u16* __restrict__ w3,
                                                  u16* __restrict__ theta,
                                                  u16* __restrict__ phiT,
                                                  u16* __restrict__ gT,
                                                  float* __restrict__ pooled) {
    const int bid = blockIdx.x;
    const int b = bid & 7, nt = bid >> 3;
    const int n0 = nt * 64;
    const int t = threadIdx.x, lane = t & 63, w = t >> 6;
    const int cl = lane & 31, h = lane >> 5;

    __shared__ u16 As[64 * 256];   // [n][c] bf16, 16B-granule swizzled ^(n&7)
    __shared__ u16 Ep[128 * 72];   // epilogue buffer

    {   // stage x[b, :, n0:n0+64] -> As (transposed to [n][c]); fused SE pooling
        const float* xb = x + ((size_t)b * C_DIM) * N_DIM + n0;
        for (int it = 0; it < 16; ++it) {
            int id = it * 256 + t;
            int c = id >> 4, l16 = id & 15;
            float4 v = *(const float4*)(xb + (size_t)c * N_DIM + l16 * 4);
            int g = c >> 3, co = c & 7;
            float vv[4] = {v.x, v.y, v.z, v.w};
            #pragma unroll
            for (int k = 0; k < 4; ++k) {
                int n = l16 * 4 + k;
                As[n * 256 + ((g ^ (n & 7)) << 3) + co] = f2bf(vv[k]);
            }
            float s = (v.x + v.y) + (v.z + v.w);
            s += __shfl_xor(s, 1); s += __shfl_xor(s, 2);
            s += __shfl_xor(s, 4); s += __shfl_xor(s, 8);
            if ((t & 15) == 0) atomicAdd(&pooled[b * C_DIM + c], s);
        }
    }
    __syncthreads();

    const int mt = w & 1;    // n-tile
    const int ip = w >> 1;   // i-pair
    bf16x8 afr[16];
    #pragma unroll
    for (int ks = 0; ks < 16; ++ks) {
        int r = mt * 32 + cl;
        int g = 2 * ks + h;
        afr[ks] = *(const bf16x8*)&As[r * 256 + ((g ^ (r & 7)) << 3)];
    }

    for (int z = 0; z < 3; ++z) {
        const u16* wz = w3 + z * (I_DIM * C_DIM);
        f32x16 acc[2] = {};
        #pragma unroll
        for (int ks = 0; ks < 16; ++ks) {
            #pragma unroll
            for (int f = 0; f < 2; ++f) {
                int irow = (2 * ip + f) * 32 + cl;
                bf16x8 bfr = *(const bf16x8*)(wz + (size_t)irow * C_DIM + ks * 16 + h * 8);
                acc[f] = __builtin_amdgcn_mfma_f32_32x32x16_bf16(afr[ks], bfr, acc[f], 0, 0, 0);
            }
        }
        if (z < 2) {
            float sc = (z == 0) ? TH_SCALE : 1.0f;
            // Ep as [n64][i 136pad]
            #pragma unroll
            for (int f = 0; f < 2; ++f) {
                int i = (2 * ip + f) * 32 + cl;
                #pragma unroll
                for (int r2 = 0; r2 < 4; ++r2)
                    #pragma unroll
                    for (int e = 0; e < 4; ++e) {
                        int n = mt * 32 + 8 * r2 + 4 * h + e;
                        Ep[n * 136 + i] = f2bf(acc[f][4 * r2 + e] * sc);
                    }
            }
            __syncthreads();
            u16* dst = (z == 0) ? theta : phiT;
            #pragma unroll
            for (int it = 0; it < 4; ++it) {
                int id = it * 256 + t;
                int n = id >> 4, l16 = id & 15;
                f32x4 vv = *(const f32x4*)&Ep[n * 136 + l16 * 8];
                *(f32x4*)(dst + ((size_t)(b * N_DIM) + n0 + n) * I_DIM + l16 * 8) = vv;
            }
            __syncthreads();
        } else {
            // Ep as [i128][n 72pad]
            #pragma unroll
            for (int f = 0; f < 2; ++f) {
                int i = (2 * ip + f) * 32 + cl;
                #pragma unroll
                for (int r2 = 0; r2 < 4; ++r2) {
                    u32 lo = pk2(acc[f][4 * r2 + 0], acc[f][4 * r2 + 1]);
                    u32 hi = pk2(acc[f][4 * r2 + 2], acc[f][4 * r2 + 3]);
                    int nb = mt * 32 + 8 * r2 + 4 * h;
                    *(u32*)&Ep[i * 72 + nb] = lo;
                    *(u32*)&Ep[i * 72 + nb + 2] = hi;
                }
            }
            __syncthreads();
            #pragma unroll
            for (int it = 0; it < 4; ++it) {
                int id = it * 256 + t;
                int i = id >> 3, l8 = id & 7;
                f32x4 vv = *(const f32x4*)&Ep[i * 72 + l8 * 8];
                *(f32x4*)(gT + ((size_t)(b * I_DIM) + i) * N_DIM + n0 + l8 * 8) = vv;
            }
        }
    }
}

// ---- 5: flash attention, "big-q": 4 waves x 64 q-rows = 256 q per block ----
// Grid = 8b x 2mh x 16qt = 256 blocks = exactly 1 block/CU; bid&7 decode keeps
// each XCD on a single batch -> K/V (2MB) L2-resident per XCD.
// Every kf/vf LDS fragment and every staged chunk now feeds 2 q-subtiles
// (2x MFMA per LDS read / DMA byte vs the 32q-wave version).
// Pipeline: raw s_barrier + s_waitcnt vmcnt(8), prefetch in flight across the
// barrier; only the last chunk drains vmcnt(0). ~290 regs/wave @ 1 wave/SIMD.
__global__ __launch_bounds__(256, 1) void attn_kernel(const u16* __restrict__ theta,
                                                      const u16* __restrict__ phiT,
                                                      const u16* __restrict__ gT,
                                                      u16* __restrict__ ao0, u16* __restrict__ ao1,
                                                      float* __restrict__ l0, float* __restrict__ l1,
                                                      const float* __restrict__ pooled,
                                                      const float* __restrict__ fc1w,
                                                      const float* __restrict__ fc1b,
                                                      const float* __restrict__ fc2w,
                                                      const float* __restrict__ fc2b,
                                                      float* __restrict__ chw) {
    const int bid = blockIdx.x;
    const int b = bid & 7, mh = (bid >> 3) & 1, qt = bid >> 4;   // qt 0..15
    const int t = threadIdx.x, lane = t & 63, w = t >> 6;
    const int cl = lane & 31, h = lane >> 5;
    const int qw = qt * 256 + w * 64;    // wave q-base (64 rows per wave)

    __shared__ __align__(16) u16 SM[32768];   // 64KB: K0 V0 K1 V1 (16KB each); reused as epilogue
    __shared__ float lexw[4][2][32];
    __shared__ float sse[512];

    bf16x8 qf[2][8];
    #pragma unroll
    for (int qs = 0; qs < 2; ++qs) {
        const u16* qp = theta + ((size_t)(b * N_DIM) + qw + qs * 32 + cl) * I_DIM + h * 8;
        #pragma unroll
        for (int ks = 0; ks < 8; ++ks) qf[qs][ks] = *(const bf16x8*)(qp + ks * 16);
    }

    const u16* kbase = phiT + (size_t)b * N_DIM * I_DIM + (size_t)(mh * 2048) * I_DIM;
    const u16* vbase = gT + (size_t)b * I_DIM * N_DIM + mh * 2048;
    const u16* kptr[4]; const u16* vptr[4];
    #pragma unroll
    for (int it = 0; it < 4; ++it) {
        int gi = (w * 4 + it) * 64 + lane;
        int kr = gi >> 4, kg = gi & 15;
        kptr[it] = kbase + (size_t)kr * I_DIM + ((kg ^ (kr & 7)) << 3);
        int vr = gi >> 3, vg = gi & 7;
        vptr[it] = vbase + (size_t)vr * N_DIM + ((vg ^ (vr & 7)) << 3);
    }

    auto issue = [&](int p) {
        u16* Kd = SM + p * 16384;
        u16* Vd = Kd + 8192;
        #pragma unroll
        for (int it = 0; it < 4; ++it) { async16(kptr[it], Kd + (w * 4 + it) * 512); kptr[it] += 64 * I_DIM; }
        #pragma unroll
        for (int it = 0; it < 4; ++it) { async16(vptr[it], Vd + (w * 4 + it) * 512); vptr[it] += 64; }
    };

    float lsum0 = 0.f, lsum1 = 0.f;
    f32x16 O0[4] = {}, O1[4] = {};

    issue(0);   // chunk 0 -> buf 0

    for (int mc = 0; mc < 32; ++mc) {
        const int p = mc & 1;
        // (A) all waves done computing chunk mc-1 -> buf 1-p is free to overwrite
        __asm__ volatile("s_barrier" ::: "memory");
        if (mc < 31) {
            issue(1 - p);   // prefetch chunk mc+1; stays in flight across barrier B
            __asm__ volatile("s_waitcnt vmcnt(8)" ::: "memory");   // own chunk-mc loads retired
        } else {
            __asm__ volatile("s_waitcnt vmcnt(0)" ::: "memory");
        }
        // (B) all waves' chunk-mc loads retired -> buf p fully populated
        __asm__ volatile("s_barrier" ::: "memory");

        const u16* Ks = SM + p * 16384;
        const u16* Vs = Ks + 8192;

        #pragma unroll
        for (int kt = 0; kt < 2; ++kt) {
            // S^T = K Q^T over 32 keys x both q-subtiles; theta pre-scaled so P = exp2(S)
            f32x16 S0 = {}, S1 = {};
            __builtin_amdgcn_s_setprio(1);
            #pragma unroll
            for (int ks = 0; ks < 8; ++ks) {
                int r = kt * 32 + cl;
                bf16x8 kf = *(const bf16x8*)&Ks[r * 128 + (((2 * ks + h) ^ (r & 7)) << 3)];
                S0 = __builtin_amdgcn_mfma_f32_32x32x16_bf16(kf, qf[0][ks], S0, 0, 0, 0);
                S1 = __builtin_amdgcn_mfma_f32_32x32x16_bf16(kf, qf[1][ks], S1, 0, 0, 0);
            }
            __builtin_amdgcn_s_setprio(0);

            u32 pk0[4][2], pk1[4][2];
            #pragma unroll
            for (int r2 = 0; r2 < 4; ++r2) {
                float a0 = __builtin_amdgcn_exp2f(S0[4 * r2 + 0]);
                float a1 = __builtin_amdgcn_exp2f(S0[4 * r2 + 1]);
                float a2 = __builtin_amdgcn_exp2f(S0[4 * r2 + 2]);
                float a3 = __builtin_amdgcn_exp2f(S0[4 * r2 + 3]);
                lsum0 += (a0 + a1) + (a2 + a3);
                pk0[r2][0] = pk2t(a0, a1);
                pk0[r2][1] = pk2t(a2, a3);
                float b0 = __builtin_amdgcn_exp2f(S1[4 * r2 + 0]);
                float b1 = __builtin_amdgcn_exp2f(S1[4 * r2 + 1]);
                float b2 = __builtin_amdgcn_exp2f(S1[4 * r2 + 2]);
                float b3 = __builtin_amdgcn_exp2f(S1[4 * r2 + 3]);
                lsum1 += (b0 + b1) + (b2 + b3);
                pk1[r2][0] = pk2t(b0, b1);
                pk1[r2][1] = pk2t(b2, b3);
            }

            // O += P V ; A-frags via v_permlane32_swap (verified construction);
            // each vf LDS read feeds BOTH q-subtiles.
            __builtin_amdgcn_s_setprio(1);
            #pragma unroll
            for (int s = 0; s < 2; ++s) {
                u32 x0 = pk0[2 * s][0], y0 = pk0[2 * s + 1][0];
                u32 x1 = pk0[2 * s][1], y1 = pk0[2 * s + 1][1];
                plswap(x0, y0);
                plswap(x1, y1);
                BF8 A0; A0.u[0] = x0; A0.u[1] = x1; A0.u[2] = y0; A0.u[3] = y1;
                u32 m0 = pk1[2 * s][0], n0_ = pk1[2 * s + 1][0];
                u32 m1 = pk1[2 * s][1], n1_ = pk1[2 * s + 1][1];
                plswap(m0, n0_);
                plswap(m1, n1_);
                BF8 A1; A1.u[0] = m0; A1.u[1] = m1; A1.u[2] = n0_; A1.u[3] = n1_;
                const int g = kt * 4 + 2 * s + h;
                #pragma unroll
                for (int f = 0; f < 4; ++f) {
                    int ir = f * 32 + cl;
                    bf16x8 vf = *(const bf16x8*)&Vs[ir * 64 + ((g ^ (ir & 7)) << 3)];
                    O0[f] = __builtin_amdgcn_mfma_f32_32x32x16_bf16(A0.v, vf, O0[f], 0, 0, 0);
                    O1[f] = __builtin_amdgcn_mfma_f32_32x32x16_bf16(A1.v, vf, O1[f], 0, 0, 0);
                }
            }
            __builtin_amdgcn_s_setprio(0);
        }
    }

    // ---- epilogue ----
    {   // h-half lsum combine, in-register (both halves end with the total)
        union { float f; u32 u; } a, b2;
        a.f = lsum0; b2.f = lsum0;
        plswap(a.u, b2.u);
        lsum0 = a.f + b2.f;
        a.f = lsum1; b2.f = lsum1;
        plswap(a.u, b2.u);
        lsum1 = a.f + b2.f;
    }
    if (h == 0) { lexw[w][0][cl] = lsum0; lexw[w][1][cl] = lsum1; }
    __syncthreads();   // all K/V reads done (SM free for epilogue) + lexw published

    u16* aop = (mh == 0) ? ao0 : ao1;
    float* lp = (mh == 0) ? l0 : l1;
    if (h == 0) {
        lp[(size_t)b * N_DIM + qw + cl] = lsum0;
        lp[(size_t)b * N_DIM + qw + 32 + cl] = lsum1;
    }

    u16* ep = SM + w * 8192;   // [q64][i128] per wave, 16KB each
    #pragma unroll
    for (int qs = 0; qs < 2; ++qs) {
        float linv[16];
        {
            float* lw = lexw[w][qs];
            #pragma unroll
            for (int r2 = 0; r2 < 4; ++r2) {
                f32x4 lv = *(const f32x4*)&lw[8 * r2 + 4 * h];
                #pragma unroll
                for (int e = 0; e < 4; ++e) linv[4 * r2 + e] = 1.f / lv[e];
            }
        }
        u16* e2 = ep + qs * 4096;
        #pragma unroll
        for (int f = 0; f < 4; ++f)
            #pragma unroll
            for (int r2 = 0; r2 < 4; ++r2)
                #pragma unroll
                for (int e = 0; e < 4; ++e) {
                    int q = 8 * r2 + 4 * h + e;
                    float ov = (qs == 0) ? O0[f][4 * r2 + e] : O1[f][4 * r2 + e];
                    e2[q * 128 + f * 32 + cl] = f2bf(ov * linv[4 * r2 + e]);
                }
    }
    __asm__ volatile("s_waitcnt lgkmcnt(0)" ::: "memory");
    #pragma unroll
    for (int it = 0; it < 16; ++it) {
        int id = it * 64 + lane;
        int q = id >> 4, l16 = id & 15;
        f32x4 vv = *(const f32x4*)&ep[q * 128 + l16 * 8];
        *(f32x4*)(aop + ((size_t)(b * N_DIM) + qw + q) * I_DIM + l16 * 8) = vv;
    }

    // ---- fused SE MLP (block 0 only; pooled complete since qkv finished) ----
    if (bid == 0) {
        const int sb = t >> 5;          // batch 0..7
        #pragma unroll
        for (int pp = 0; pp < 2; ++pp) {
            int j = (t & 31) + pp * 32; // hidden unit 0..63
            float d = 0.f;
            for (int c = 0; c < C_DIM; c += 4) {
                float4 pv = *(const float4*)(pooled + sb * C_DIM + c);
                float4 wv = *(const float4*)(fc1w + j * C_DIM + c);
                d += (pv.x * wv.x + pv.y * wv.y) + (pv.z * wv.z + pv.w * wv.w);
            }
            float a = fc1b[j] + d * (1.f / N_DIM);
            sse[sb * 64 + j] = a > 0.f ? a : 0.f;
        }
        __syncthreads();
        const int c0 = (t & 31) * 8;
        #pragma unroll
        for (int r = 0; r < 8; ++r) {
            int c = c0 + r;
            float acc = fc2b[c];
            for (int k = 0; k < R_DIM; k += 4) {
                float4 wv = *(const float4*)(fc2w + c * R_DIM + k);
                acc += (sse[sb * 64 + k] * wv.x + sse[sb * 64 + k + 1] * wv.y)
                     + (sse[sb * 64 + k + 2] * wv.z + sse[sb * 64 + k + 3] * wv.w);
            }
            chw[sb * C_DIM + c] = 1.f / (1.f + __builtin_amdgcn_exp2f(-acc * 1.44269504089f));
        }
    }
}

// ---- 6: out projection + partial combine + BN stats ----
__global__ __launch_bounds__(256) void oproj_kernel(const u16* __restrict__ ao0,
                                                    const u16* __restrict__ ao1,
                                                    const float* __restrict__ l0,
                                                    const float* __restrict__ l1,
                                                    const u16* __restrict__ owb,
                                                    u16* __restrict__ out2,
                                                    float* __restrict__ bnsum,
                                                    float* __restrict__ bnsumsq) {
    const int bid = blockIdx.x;
    const int b = bid & 7, nt = bid >> 3;
    const int n0 = nt * 64;
    const int t = threadIdx.x, lane = t & 63, w = t >> 6;
    const int cl = lane & 31, h = lane >> 5;

    __shared__ u16 Ep[256 * 72];   // [c][n 72pad]
    __shared__ float lsum[C_DIM], lsq[C_DIM];
    lsum[t] = 0.f; lsq[t] = 0.f;
    __syncthreads();

    const int mt = w & 1;
    const int nn = n0 + mt * 32 + cl;
    float w0, w1;
    {
        float la = l0[(size_t)b * N_DIM + nn], lb = l1[(size_t)b * N_DIM + nn];
        float inv = 1.f / (la + lb);
        w0 = la * inv; w1 = lb * inv;
    }
    bf16x8 afr[8];
    {
        const u16* p0 = ao0 + ((size_t)(b * N_DIM) + nn) * I_DIM + h * 8;
        const u16* p1 = ao1 + ((size_t)(b * N_DIM) + nn) * I_DIM + h * 8;
        #pragma unroll
        for (int ks = 0; ks < 8; ++ks) {
            bf16x8 x0 = *(const bf16x8*)(p0 + ks * 16);
            bf16x8 x1 = *(const bf16x8*)(p1 + ks * 16);
            const u16* u0 = (const u16*)&x0;
            const u16* u1 = (const u16*)&x1;
            float c0 = w0 * bf2f(u0[0]) + w1 * bf2f(u1[0]);
            float c1 = w0 * bf2f(u0[1]) + w1 * bf2f(u1[1]);
            float c2 = w0 * bf2f(u0[2]) + w1 * bf2f(u1[2]);
            float c3 = w0 * bf2f(u0[3]) + w1 * bf2f(u1[3]);
            float c4 = w0 * bf2f(u0[4]) + w1 * bf2f(u1[4]);
            float c5 = w0 * bf2f(u0[5]) + w1 * bf2f(u1[5]);
            float c6 = w0 * bf2f(u0[6]) + w1 * bf2f(u1[6]);
            float c7 = w0 * bf2f(u0[7]) + w1 * bf2f(u1[7]);
            BF8 r;
            r.u[0] = pk2(c0, c1); r.u[1] = pk2(c2, c3);
            r.u[2] = pk2(c4, c5); r.u[3] = pk2(c6, c7);
            afr[ks] = r.v;
        }
    }

    f32x16 D[4] = {};
    #pragma unroll
    for (int ks = 0; ks < 8; ++ks) {
        #pragma unroll
        for (int j = 0; j < 4; ++j) {
            int cr = ((w >> 1) * 4 + j) * 32 + cl;
            bf16x8 bfr = *(const bf16x8*)(owb + (size_t)cr * I_DIM + ks * 16 + h * 8);
            D[j] = __builtin_amdgcn_mfma_f32_32x32x16_bf16(afr[ks], bfr, D[j], 0, 0, 0);
        }
    }

    #pragma unroll
    for (int j = 0; j < 4; ++j) {
        int c = ((w >> 1) * 4 + j) * 32 + cl;
        float s1 = 0.f, s2 = 0.f;
        #pragma unroll
        for (int r2 = 0; r2 < 4; ++r2) {
            float v0 = D[j][4 * r2 + 0], v1 = D[j][4 * r2 + 1];
            float v2 = D[j][4 * r2 + 2], v3 = D[j][4 * r2 + 3];
            s1 += (v0 + v1) + (v2 + v3);
            s2 += (v0 * v0 + v1 * v1) + (v2 * v2 + v3 * v3);
            int nb = mt * 32 + 8 * r2 + 4 * h;
            *(u32*)&Ep[c * 72 + nb] = pk2(v0, v1);
            *(u32*)&Ep[c * 72 + nb + 2] = pk2(v2, v3);
        }
        atomicAdd(&lsum[c], s1);
        atomicAdd(&lsq[c], s2);
    }
    __syncthreads();
    #pragma unroll
    for (int it = 0; it < 8; ++it) {
        int id = it * 256 + t;
        int c = id >> 3, l8 = id & 7;
        f32x4 vv = *(const f32x4*)&Ep[c * 72 + l8 * 8];
        *(f32x4*)(out2 + ((size_t)(b * C_DIM) + c) * N_DIM + n0 + l8 * 8) = vv;
    }
    atomicAdd(&bnsum[t], lsum[t]);
    atomicAdd(&bnsumsq[t], lsq[t]);
}

// ---- 7: BN normalize + SE scale + residual ----
__global__ void final_kernel(const float* __restrict__ x, const u16* __restrict__ out2,
                             const float* __restrict__ bnsum, const float* __restrict__ bnsumsq,
                             const float* __restrict__ gamma, const float* __restrict__ beta,
                             const float* __restrict__ chw, float* __restrict__ out) {
    int idx = blockIdx.x * 256 + threadIdx.x;
    int e = idx * 4;
    int b = e >> 20;
    int c = (e >> 12) & 255;
    float mean = bnsum[c] * (1.f / 32768.f);
    float var = bnsumsq[c] * (1.f / 32768.f) - mean * mean;
    float sc = gamma[c] * rsqrtf(var + 1e-5f);
    float sh = beta[c] - mean * sc;
    float cw = chw[b * C_DIM + c];
    ushort4 o16 = ((const ushort4*)out2)[idx];
    float4 xv = ((const float4*)x)[idx];
    float4 res;
    res.x = xv.x + (bf2f(o16.x) * sc + sh) * cw;
    res.y = xv.y + (bf2f(o16.y) * sc + sh) * cw;
    res.z = xv.z + (bf2f(o16.z) * sc + sh) * cw;
    res.w = xv.w + (bf2f(o16.w) * sc + sh) * cw;
    ((float4*)out)[idx] = res;
}

extern "C" void kernel_launch(void* const* d_in, const int* in_sizes, int n_in,
                              void* d_out, int out_size, void* d_ws, size_t ws_size,
                              hipStream_t stream) {
    const float* x   = (const float*)d_in[0];
    const float* tw  = (const float*)d_in[1];
    const float* pw  = (const float*)d_in[2];
    const float* gw  = (const float*)d_in[3];
    const float* ow  = (const float*)d_in[4];
    const float* gam = (const float*)d_in[5];
    const float* bet = (const float*)d_in[6];
    const float* f1w = (const float*)d_in[7];
    const float* f1b = (const float*)d_in[8];
    const float* f2w = (const float*)d_in[9];
    const float* f2b = (const float*)d_in[10];
    float* out = (float*)d_out;

    char* ws = (char*)d_ws;
    float* bnsum   = (float*)(ws + OFF_BNSUM);
    float* bnsumsq = (float*)(ws + OFF_BNSQ);
    float* pooled  = (float*)(ws + OFF_POOL);
    float* chw     = (float*)(ws + OFF_CHW);
    u16*   w3      = (u16*)(ws + OFF_W3);
    u16*   owb     = (u16*)(ws + OFF_OWB);
    u16*   ao0     = (u16*)(ws + OFF_AO0);
    u16*   ao1     = (u16*)(ws + OFF_AO1);
    u16*   theta   = (u16*)(ws + OFF_THETA);
    u16*   phiT    = (u16*)(ws + OFF_PHIT);
    u16*   gT      = (u16*)(ws + OFF_GT);
    float* l0      = (float*)(ws + OFF_L0);
    float* l1      = (float*)(ws + OFF_L1);
    u16*   out2    = (u16*)(ws + OFF_OUT2);

    prep_kernel<<<384, 256, 0, stream>>>(tw, pw, gw, ow, w3, owb, bnsum, pooled);
    qkv_kernel<<<512, 256, 0, stream>>>(x, w3, theta, phiT, gT, pooled);
    attn_kernel<<<256, 256, 0, stream>>>(theta, phiT, gT, ao0, ao1, l0, l1,
                                         pooled, f1w, f1b, f2w, f2b, chw);
    oproj_kernel<<<512, 256, 0, stream>>>(ao0, ao1, l0, l1, owb, out2, bnsum, bnsumsq);
    final_kernel<<<8192, 256, 0, stream>>>(x, out2, bnsum, bnsumsq, gam, bet, chw, out);
}